// Round 4
// baseline (309.737 us; speedup 1.0000x reference)
//
#include <hip/hip_runtime.h>

constexpr int B = 8, C = 128, H = 64, W = 64, O = 128;
constexpr int K2 = 9;
constexpr int HW = H * W; // 4096

typedef __bf16 bf16x8 __attribute__((ext_vector_type(8)));
typedef float f32x4 __attribute__((ext_vector_type(4)));
typedef float f32x16 __attribute__((ext_vector_type(16)));
typedef unsigned int ux4 __attribute__((ext_vector_type(4)));

static __device__ __forceinline__ unsigned pack_pair(__bf16 a, __bf16 b) {
    unsigned short ua = __builtin_bit_cast(unsigned short, a);
    unsigned short ub = __builtin_bit_cast(unsigned short, b);
    return (unsigned)ua | ((unsigned)ub << 16);
}

// ---------------- kernel 0a: weight split to bf16 hi/lo ----------------
// wBhi/wBlo[chunk=tap*4+ch][o][32 cc] = split(weight[o][ch*32+cc][tap])
__global__ void wsplit_kernel(const float* __restrict__ w,
                              __bf16* __restrict__ wBhi, __bf16* __restrict__ wBlo) {
    int idx = blockIdx.x * 256 + threadIdx.x; // [0, 36*128*32)
    int kk = idx & 31;
    int o = (idx >> 5) & 127;
    int chunk = idx >> 12;
    int tap = chunk >> 2, ch = chunk & 3;
    int c = ch * 32 + kk;
    float v = w[(o * C + c) * 9 + tap];
    __bf16 h = (__bf16)v;
    wBhi[idx] = h;
    wBlo[idx] = (__bf16)(v - (float)h);
}

// ---------------- kernel 0b: offset-weight transpose ----------------
__global__ void otrans_kernel(const float* __restrict__ ow, float* __restrict__ owT) {
    int idx = blockIdx.x * 256 + threadIdx.x; // [0, 128*9*18)
    if (idx >= C * 9 * 18) return;
    int oc = idx % 18;
    int tap = (idx / 18) % 9;
    int c = idx / (18 * 9);
    owT[(c * 9 + tap) * 20 + oc] = ow[(oc * C + c) * 9 + tap];
}

// ---------------- kernel 1: offset conv (18 out-ch, 3x3, pad=1) ----------------
__global__ __launch_bounds__(256) void offconv_kernel(
    const float* __restrict__ x, const float* __restrict__ owT,
    const float* __restrict__ ob, float* __restrict__ offs) {
    __shared__ float s_red[4][18][64];
    int t = threadIdx.x;
    int bid = blockIdx.x;
    int b = bid >> 6, y = bid & 63;
    int px = t & 63;
    int cg = t >> 6;
    float m[9];
    int aoff[9];
#pragma unroll
    for (int kh = 0; kh < 3; ++kh)
#pragma unroll
        for (int kw = 0; kw < 3; ++kw) {
            int yy = y + kh - 1, xx = px + kw - 1;
            bool v = (yy >= 0 && yy < H && xx >= 0 && xx < W);
            m[kh * 3 + kw] = v ? 1.f : 0.f;
            aoff[kh * 3 + kw] = min(max(yy, 0), H - 1) * W + min(max(xx, 0), W - 1);
        }
    float acc[18];
#pragma unroll
    for (int o = 0; o < 18; ++o) acc[o] = 0.f;
    const float* xb = x + (b * C + cg * 32) * HW;
    const float* wb = owT + cg * 32 * 9 * 20;
    for (int c = 0; c < 32; ++c) {
        const float* xp = xb + c * HW;
        const float* wp = wb + c * 9 * 20;
#pragma unroll
        for (int tp = 0; tp < 9; ++tp) {
            float xv = m[tp] * xp[aoff[tp]];
            float4 w0 = *(const float4*)&wp[tp * 20 + 0];
            float4 w1 = *(const float4*)&wp[tp * 20 + 4];
            float4 w2 = *(const float4*)&wp[tp * 20 + 8];
            float4 w3 = *(const float4*)&wp[tp * 20 + 12];
            float2 w4 = *(const float2*)&wp[tp * 20 + 16];
            acc[0] += xv * w0.x;  acc[1] += xv * w0.y;  acc[2] += xv * w0.z;  acc[3] += xv * w0.w;
            acc[4] += xv * w1.x;  acc[5] += xv * w1.y;  acc[6] += xv * w1.z;  acc[7] += xv * w1.w;
            acc[8] += xv * w2.x;  acc[9] += xv * w2.y;  acc[10] += xv * w2.z; acc[11] += xv * w2.w;
            acc[12] += xv * w3.x; acc[13] += xv * w3.y; acc[14] += xv * w3.z; acc[15] += xv * w3.w;
            acc[16] += xv * w4.x; acc[17] += xv * w4.y;
        }
    }
#pragma unroll
    for (int o = 0; o < 18; ++o) s_red[t >> 6][o][px] = acc[o];
    __syncthreads();
    for (int flat = t; flat < 18 * 64; flat += 256) {
        int oc = flat >> 6, p = flat & 63;
        float v = ob[oc] + s_red[0][oc][p] + s_red[1][oc][p] + s_red[2][oc][p] + s_red[3][oc][p];
        offs[(b * 18 + oc) * HW + y * W + p] = v;
    }
}

// ---------------- kernel 2: bilinear sample + MFMA GEMM (bf16 hi/lo 3-pass) ----
// grid = B*H (one row, M=64 px), 256 thr = 4 waves; wave = 32px x 64o (2 tiles 32x32)
// K = 9 taps x 128 c = 36 chunks of 32; per chunk: stage A(sampled, hi/lo) + B(wB hi/lo)
__global__ __launch_bounds__(256, 3) void deform_kernel(
    const float* __restrict__ x, const float* __restrict__ offs,
    const __bf16* __restrict__ wBhi, const __bf16* __restrict__ wBlo,
    const float* __restrict__ bias, float* __restrict__ out) {
    // A planes: [k8-unit u][px][8 bf16] = 256 x 16B; B: [o][4 units swz] = 512 x 16B
    __shared__ ux4 Ah[2][256], Al[2][256];
    __shared__ ux4 Bh[2][512], Bl[2][512];

    int t = threadIdx.x;
    int bid = blockIdx.x;
    bid = ((bid & 7) << 6) | (bid >> 3); // XCD swizzle, 512 % 8 == 0 -> bijective
    int b = bid >> 6, y = bid & 63;
    int row0 = y * W;
    const float* xb = x + b * C * HW;

    int px = t & 63;   // sampling pixel
    int su = t >> 6;   // sampling k8-unit
    int l31 = t & 31;
    int lhi = (t >> 5) & 1;
    int wv = t >> 6;
    int wm = wv & 1, wn = wv >> 1;

    float w00, w01, w10, w11;
    int a00, a01, a10, a11;

    auto calc = [&](int k) {
        int kh = k / 3, kw = k % 3;
        float dy = offs[(b * 18 + 2 * k) * HW + row0 + px];
        float dx = offs[(b * 18 + 2 * k + 1) * HW + row0 + px];
        float ys = (float)(y - 1 + kh) + dy;
        float xs = (float)(px - 1 + kw) + dx;
        float yf = floorf(ys), xf = floorf(xs);
        int iy0 = (int)yf, ix0 = (int)xf;
        int iy1 = iy0 + 1, ix1 = ix0 + 1;
        float wy1 = ys - yf, wy0 = 1.f - wy1;
        float wx1 = xs - xf, wx0 = 1.f - wx1;
        bool vy0 = (iy0 >= 0) & (iy0 < H), vy1 = (iy1 >= 0) & (iy1 < H);
        bool vx0 = (ix0 >= 0) & (ix0 < W), vx1 = (ix1 >= 0) & (ix1 < W);
        int iy0c = min(max(iy0, 0), H - 1), iy1c = min(max(iy1, 0), H - 1);
        int ix0c = min(max(ix0, 0), W - 1), ix1c = min(max(ix1, 0), W - 1);
        w00 = (vy0 && vx0) ? wy0 * wx0 : 0.f;
        w01 = (vy0 && vx1) ? wy0 * wx1 : 0.f;
        w10 = (vy1 && vx0) ? wy1 * wx0 : 0.f;
        w11 = (vy1 && vx1) ? wy1 * wx1 : 0.f;
        a00 = iy0c * W + ix0c;
        a01 = iy0c * W + ix1c;
        a10 = iy1c * W + ix0c;
        a11 = iy1c * W + ix1c;
    };

    auto stage = [&](int chunk, int bi) {
        int tap = chunk >> 2, ch = chunk & 3;
        // B: 8KB hi + 8KB lo; thread stages 2 units each; XOR-swizzled dest
        const __bf16* sh = wBhi + chunk * 4096;
        const __bf16* sl = wBlo + chunk * 4096;
#pragma unroll
        for (int i = 0; i < 2; ++i) {
            int idx = i * 256 + t;
            int o = idx >> 2, u = idx & 3;
            int du = u ^ ((o >> 1) & 3);
            ux4 vh = *(const ux4*)(sh + idx * 8);
            ux4 vl = *(const ux4*)(sl + idx * 8);
            Bh[bi][o * 4 + du] = vh;
            Bl[bi][o * 4 + du] = vl;
        }
        // A: bilinear sample 8 c's of this thread's px, split hi/lo
        if (ch == 0) calc(tap);
        int c0 = ch * 32 + su * 8;
        float vv[8];
#pragma unroll
        for (int e = 0; e < 8; ++e) {
            const float* p = xb + (c0 + e) * HW;
            vv[e] = w00 * p[a00] + w01 * p[a01] + w10 * p[a10] + w11 * p[a11];
        }
        ux4 qh, ql;
#pragma unroll
        for (int e2 = 0; e2 < 4; ++e2) {
            float v0 = vv[2 * e2], v1 = vv[2 * e2 + 1];
            __bf16 h0 = (__bf16)v0, h1 = (__bf16)v1;
            __bf16 r0 = (__bf16)(v0 - (float)h0), r1 = (__bf16)(v1 - (float)h1);
            qh[e2] = pack_pair(h0, h1);
            ql[e2] = pack_pair(r0, r1);
        }
        Ah[bi][su * 64 + px] = qh;
        Al[bi][su * 64 + px] = ql;
    };

    f32x16 acc[2];
#pragma unroll
    for (int tn = 0; tn < 2; ++tn) {
        float bv = bias[wn * 64 + tn * 32 + l31];
#pragma unroll
        for (int j = 0; j < 16; ++j) acc[tn][j] = bv;
    }

    stage(0, 0);
    __syncthreads();
#pragma unroll 1
    for (int i = 0; i < 36; ++i) {
        if (i < 35) stage(i + 1, (i + 1) & 1);
        int bi = i & 1;
#pragma unroll
        for (int s = 0; s < 2; ++s) {
            int u = s * 2 + lhi;
            bf16x8 ah = __builtin_bit_cast(bf16x8, Ah[bi][u * 64 + wm * 32 + l31]);
            bf16x8 al = __builtin_bit_cast(bf16x8, Al[bi][u * 64 + wm * 32 + l31]);
#pragma unroll
            for (int tn = 0; tn < 2; ++tn) {
                int o = wn * 64 + tn * 32 + l31;
                int du = u ^ ((o >> 1) & 3);
                bf16x8 bh = __builtin_bit_cast(bf16x8, Bh[bi][o * 4 + du]);
                bf16x8 bl = __builtin_bit_cast(bf16x8, Bl[bi][o * 4 + du]);
                acc[tn] = __builtin_amdgcn_mfma_f32_32x32x16_bf16(ah, bh, acc[tn], 0, 0, 0);
                acc[tn] = __builtin_amdgcn_mfma_f32_32x32x16_bf16(al, bh, acc[tn], 0, 0, 0);
                acc[tn] = __builtin_amdgcn_mfma_f32_32x32x16_bf16(ah, bl, acc[tn], 0, 0, 0);
            }
        }
        __syncthreads();
    }

    // C/D layout 32x32: col = l31 (o), row = (reg&3) + 8*(reg>>2) + 4*lhi (px-local)
#pragma unroll
    for (int tn = 0; tn < 2; ++tn) {
        int o = wn * 64 + tn * 32 + l31;
        float* op = out + (b * O + o) * HW + row0;
#pragma unroll
        for (int g = 0; g < 4; ++g) {
            int pxo = wm * 32 + g * 8 + lhi * 4;
            f32x4 v4;
            v4[0] = acc[tn][g * 4 + 0];
            v4[1] = acc[tn][g * 4 + 1];
            v4[2] = acc[tn][g * 4 + 2];
            v4[3] = acc[tn][g * 4 + 3];
            *(f32x4*)(op + pxo) = v4;
        }
    }
}

extern "C" void kernel_launch(void* const* d_in, const int* in_sizes, int n_in,
                              void* d_out, int out_size, void* d_ws, size_t ws_size,
                              hipStream_t stream) {
    const float* x        = (const float*)d_in[0];
    const float* offset_w = (const float*)d_in[1];
    const float* offset_b = (const float*)d_in[2];
    const float* weight   = (const float*)d_in[3];
    const float* bias     = (const float*)d_in[4];
    float* out = (float*)d_out;
    float* offs = (float*)d_ws;                  // 8*18*4096 floats = 589824
    float* owT = offs + B * 18 * HW;             // 128*9*20 = 23040 floats
    __bf16* wBhi = (__bf16*)(owT + 128 * 9 * 20); // 36*128*32 bf16
    __bf16* wBlo = wBhi + 36 * 128 * 32;

    wsplit_kernel<<<576, 256, 0, stream>>>(weight, wBhi, wBlo);
    otrans_kernel<<<(C * 9 * 18 + 255) / 256, 256, 0, stream>>>(offset_w, owT);
    offconv_kernel<<<B * H, 256, 0, stream>>>(x, owT, offset_b, offs);
    deform_kernel<<<B * H, 256, 0, stream>>>(x, offs, wBhi, wBlo, bias, out);
}

// Round 5
// 245.234 us; speedup vs baseline: 1.2630x; 1.2630x over previous
//
#include <hip/hip_runtime.h>

constexpr int B = 8, C = 128, H = 64, W = 64, O = 128;
constexpr int HW = H * W; // 4096

typedef __bf16 bf16x8 __attribute__((ext_vector_type(8)));
typedef float f32x4 __attribute__((ext_vector_type(4)));
typedef float f32x16 __attribute__((ext_vector_type(16)));
typedef unsigned int ux4 __attribute__((ext_vector_type(4)));

static __device__ __forceinline__ unsigned pack_pair(__bf16 a, __bf16 b) {
    unsigned short ua = __builtin_bit_cast(unsigned short, a);
    unsigned short ub = __builtin_bit_cast(unsigned short, b);
    return (unsigned)ua | ((unsigned)ub << 16);
}

// ---------------- kernel 0a: weight split to bf16 hi/lo ----------------
// wBhi/wBlo[chunk=tap*4+ch][o][32 cc] = split(weight[o][ch*32+cc][tap])
__global__ void wsplit_kernel(const float* __restrict__ w,
                              __bf16* __restrict__ wBhi, __bf16* __restrict__ wBlo) {
    int idx = blockIdx.x * 256 + threadIdx.x; // [0, 36*128*32)
    int kk = idx & 31;
    int o = (idx >> 5) & 127;
    int chunk = idx >> 12;
    int tap = chunk >> 2, ch = chunk & 3;
    int c = ch * 32 + kk;
    float v = w[(o * C + c) * 9 + tap];
    __bf16 h = (__bf16)v;
    wBhi[idx] = h;
    wBlo[idx] = (__bf16)(v - (float)h);
}

// ---------------- kernel 0b: offset-weight transpose: owT[c][tap][20] ----------
__global__ void otrans_kernel(const float* __restrict__ ow, float* __restrict__ owT) {
    int idx = blockIdx.x * 256 + threadIdx.x; // [0, 128*9*18)
    if (idx >= C * 9 * 18) return;
    int oc = idx % 18;
    int tap = (idx / 18) % 9;
    int c = idx / (18 * 9);
    owT[(c * 9 + tap) * 20 + oc] = ow[(oc * C + c) * 9 + tap];
}

// ---------------- kernel 1: offset conv partials ----------------
// grid = 2048 = (b*64+y)*4 + cg ; block covers 64 px x 32 c (4 sub x 8 c)
__global__ __launch_bounds__(256) void offconv_part_kernel(
    const float* __restrict__ x, const float* __restrict__ owT,
    float* __restrict__ part) {
    __shared__ float ws[32 * 9 * 20];      // 23040 B
    __shared__ float s_red[4][18][64];     // 18432 B
    int t = threadIdx.x;
    int bid = blockIdx.x;
    int swz = (bid & 7) * 256 + (bid >> 3); // XCD swizzle, 2048%8==0
    int cg = swz & 3;
    int y = (swz >> 2) & 63;
    int b = swz >> 8;
    int px = t & 63, sub = t >> 6;
    const float* src = owT + cg * 5760;
    for (int i = t; i < 5760; i += 256) ws[i] = src[i];
    float m[9];
    int aoff[9];
#pragma unroll
    for (int kh = 0; kh < 3; ++kh)
#pragma unroll
        for (int kw = 0; kw < 3; ++kw) {
            int yy = y + kh - 1, xx = px + kw - 1;
            bool v = (yy >= 0 && yy < H && xx >= 0 && xx < W);
            m[kh * 3 + kw] = v ? 1.f : 0.f;
            aoff[kh * 3 + kw] = min(max(yy, 0), H - 1) * W + min(max(xx, 0), W - 1);
        }
    __syncthreads();
    float acc[18];
#pragma unroll
    for (int o = 0; o < 18; ++o) acc[o] = 0.f;
    const float* xcg = x + (b * C + cg * 32 + sub * 8) * HW;
    for (int c8 = 0; c8 < 8; ++c8) {
        const float* xp = xcg + c8 * HW;
        float xv[9];
#pragma unroll
        for (int tp = 0; tp < 9; ++tp) xv[tp] = m[tp] * xp[aoff[tp]];
        const float* wp = ws + (sub * 8 + c8) * 180;
#pragma unroll
        for (int tp = 0; tp < 9; ++tp) {
            float v = xv[tp];
            float4 w0 = *(const float4*)&wp[tp * 20 + 0];
            float4 w1 = *(const float4*)&wp[tp * 20 + 4];
            float4 w2 = *(const float4*)&wp[tp * 20 + 8];
            float4 w3 = *(const float4*)&wp[tp * 20 + 12];
            float2 w4 = *(const float2*)&wp[tp * 20 + 16];
            acc[0] += v * w0.x;  acc[1] += v * w0.y;  acc[2] += v * w0.z;  acc[3] += v * w0.w;
            acc[4] += v * w1.x;  acc[5] += v * w1.y;  acc[6] += v * w1.z;  acc[7] += v * w1.w;
            acc[8] += v * w2.x;  acc[9] += v * w2.y;  acc[10] += v * w2.z; acc[11] += v * w2.w;
            acc[12] += v * w3.x; acc[13] += v * w3.y; acc[14] += v * w3.z; acc[15] += v * w3.w;
            acc[16] += v * w4.x; acc[17] += v * w4.y;
        }
    }
#pragma unroll
    for (int o = 0; o < 18; ++o) s_red[sub][o][px] = acc[o];
    __syncthreads();
    for (int flat = t; flat < 18 * 64; flat += 256) {
        int oc = flat >> 6, p = flat & 63;
        float v = s_red[0][oc][p] + s_red[1][oc][p] + s_red[2][oc][p] + s_red[3][oc][p];
        part[(cg * B + b) * 18 * HW + oc * HW + y * 64 + p] = v;
    }
}

// ---------------- kernel 1b: reduce partials + bias ----------------
__global__ void offreduce_kernel(const float* __restrict__ part,
                                 const float* __restrict__ ob,
                                 float* __restrict__ offs) {
    int idx = blockIdx.x * 256 + threadIdx.x; // [0, 8*18*4096)
    int oc = (idx >> 12) % 18;
    constexpr int S = B * 18 * HW; // 589824
    offs[idx] = ob[oc] + part[idx] + part[S + idx] + part[2 * S + idx] + part[3 * S + idx];
}

// ---------------- kernel 2: bilinear sample + MFMA GEMM (bf16 hi/lo 3-pass) ----
// grid = 1024 (b, y, half-row of 32 px); 4 waves, wave = 32px x 32o
// A (sampled) in 8KB double-buffered LDS; B (weights) in per-lane registers from L2
__global__ __launch_bounds__(256, 4) void deform_kernel(
    const float* __restrict__ x, const float* __restrict__ offs,
    const __bf16* __restrict__ wBhi, const __bf16* __restrict__ wBlo,
    const float* __restrict__ bias, float* __restrict__ out) {
    __shared__ uint2 Ah[2][256], Al[2][256]; // [u=4][px=32][h=2] uint2 -> 8KB total

    int t = threadIdx.x;
    int bid = blockIdx.x;
    int swz = (bid & 7) * 128 + (bid >> 3); // XCD swizzle, 1024%8==0
    int b = swz >> 7;
    int y = (swz >> 1) & 63;
    int half = swz & 1;
    int px0 = half * 32;
    int row0 = y * W;
    const float* xb = x + b * C * HW;

    int l31 = t & 31, lhi = (t >> 5) & 1, wv = t >> 6;
    int o = wv * 32 + l31;     // this lane's output channel
    int spx = t & 31;          // sampling pixel (local)
    int g = t >> 5;            // sampling c-quad 0..7 (4 c's each)

    float w00, w01, w10, w11;
    int a00, a01, a10, a11;

    auto calc = [&](int tap) {
        int kh = tap / 3, kw = tap % 3;
        int pxg = px0 + spx;
        float dy = offs[(b * 18 + 2 * tap) * HW + row0 + pxg];
        float dx = offs[(b * 18 + 2 * tap + 1) * HW + row0 + pxg];
        float ys = (float)(y - 1 + kh) + dy;
        float xs = (float)(pxg - 1 + kw) + dx;
        float yf = floorf(ys), xf = floorf(xs);
        int iy0 = (int)yf, ix0 = (int)xf;
        int iy1 = iy0 + 1, ix1 = ix0 + 1;
        float wy1 = ys - yf, wy0 = 1.f - wy1;
        float wx1 = xs - xf, wx0 = 1.f - wx1;
        bool vy0 = (iy0 >= 0) & (iy0 < H), vy1 = (iy1 >= 0) & (iy1 < H);
        bool vx0 = (ix0 >= 0) & (ix0 < W), vx1 = (ix1 >= 0) & (ix1 < W);
        int iy0c = min(max(iy0, 0), H - 1), iy1c = min(max(iy1, 0), H - 1);
        int ix0c = min(max(ix0, 0), W - 1), ix1c = min(max(ix1, 0), W - 1);
        w00 = (vy0 && vx0) ? wy0 * wx0 : 0.f;
        w01 = (vy0 && vx1) ? wy0 * wx1 : 0.f;
        w10 = (vy1 && vx0) ? wy1 * wx0 : 0.f;
        w11 = (vy1 && vx1) ? wy1 * wx1 : 0.f;
        a00 = iy0c * W + ix0c;
        a01 = iy0c * W + ix1c;
        a10 = iy1c * W + ix0c;
        a11 = iy1c * W + ix1c;
    };

    float gv[16]; // 4 c's x 4 corners, in flight during MFMA
    auto issueA = [&](int chunk) {
        int tap = chunk >> 2, ch = chunk & 3;
        if ((chunk & 3) == 0) calc(tap);
        int c0 = ch * 32 + g * 4;
#pragma unroll
        for (int e = 0; e < 4; ++e) {
            const float* p = xb + (c0 + e) * HW;
            gv[e * 4 + 0] = p[a00];
            gv[e * 4 + 1] = p[a01];
            gv[e * 4 + 2] = p[a10];
            gv[e * 4 + 3] = p[a11];
        }
    };
    auto finishA = [&](int bi) {
        uint2 qh, ql;
#pragma unroll
        for (int e2 = 0; e2 < 2; ++e2) {
            float v0 = w00 * gv[e2 * 8 + 0] + w01 * gv[e2 * 8 + 1] + w10 * gv[e2 * 8 + 2] + w11 * gv[e2 * 8 + 3];
            float v1 = w00 * gv[e2 * 8 + 4] + w01 * gv[e2 * 8 + 5] + w10 * gv[e2 * 8 + 6] + w11 * gv[e2 * 8 + 7];
            __bf16 h0 = (__bf16)v0, h1 = (__bf16)v1;
            __bf16 r0 = (__bf16)(v0 - (float)h0), r1 = (__bf16)(v1 - (float)h1);
            unsigned ph = pack_pair(h0, h1);
            unsigned pl = pack_pair(r0, r1);
            if (e2 == 0) { qh.x = ph; ql.x = pl; } else { qh.y = ph; ql.y = pl; }
        }
        int idx = (g >> 1) * 64 + spx * 2 + (g & 1);
        Ah[bi][idx] = qh;
        Al[bi][idx] = ql;
    };

    ux4 bhc[2], blc[2], bhn[2], bln[2];
    auto issueB = [&](int chunk, ux4* bh, ux4* bl) {
        const __bf16* ph = wBhi + chunk * 4096 + o * 32 + lhi * 8;
        const __bf16* pl = wBlo + chunk * 4096 + o * 32 + lhi * 8;
        bh[0] = *(const ux4*)(ph);
        bh[1] = *(const ux4*)(ph + 16);
        bl[0] = *(const ux4*)(pl);
        bl[1] = *(const ux4*)(pl + 16);
    };

    f32x16 acc;
    {
        float bv = bias[o];
#pragma unroll
        for (int j = 0; j < 16; ++j) acc[j] = bv;
    }

    issueB(0, bhc, blc);
    issueA(0);
    finishA(0);
    __syncthreads();
#pragma unroll 1
    for (int i = 0; i < 36; ++i) {
        int bi = i & 1;
        if (i < 35) {
            issueB(i + 1, bhn, bln);
            issueA(i + 1);
        }
#pragma unroll
        for (int s = 0; s < 2; ++s) {
            int u = s * 2 + lhi;
            bf16x8 ah = __builtin_bit_cast(bf16x8, *(const ux4*)&Ah[bi][u * 64 + l31 * 2]);
            bf16x8 al = __builtin_bit_cast(bf16x8, *(const ux4*)&Al[bi][u * 64 + l31 * 2]);
            bf16x8 bh = __builtin_bit_cast(bf16x8, bhc[s]);
            bf16x8 bl = __builtin_bit_cast(bf16x8, blc[s]);
            acc = __builtin_amdgcn_mfma_f32_32x32x16_bf16(ah, bh, acc, 0, 0, 0);
            acc = __builtin_amdgcn_mfma_f32_32x32x16_bf16(al, bh, acc, 0, 0, 0);
            acc = __builtin_amdgcn_mfma_f32_32x32x16_bf16(ah, bl, acc, 0, 0, 0);
        }
        if (i < 35) finishA(bi ^ 1);
        __syncthreads();
        bhc[0] = bhn[0]; bhc[1] = bhn[1];
        blc[0] = bln[0]; blc[1] = bln[1];
    }

    // C/D: col = l31 (o), row = (reg&3) + 8*(reg>>2) + 4*lhi  (px within 32)
    float* op = out + (b * O + o) * HW + row0 + px0;
#pragma unroll
    for (int gq = 0; gq < 4; ++gq) {
        f32x4 v4;
        v4[0] = acc[gq * 4 + 0];
        v4[1] = acc[gq * 4 + 1];
        v4[2] = acc[gq * 4 + 2];
        v4[3] = acc[gq * 4 + 3];
        *(f32x4*)(op + gq * 8 + lhi * 4) = v4;
    }
}

extern "C" void kernel_launch(void* const* d_in, const int* in_sizes, int n_in,
                              void* d_out, int out_size, void* d_ws, size_t ws_size,
                              hipStream_t stream) {
    const float* x        = (const float*)d_in[0];
    const float* offset_w = (const float*)d_in[1];
    const float* offset_b = (const float*)d_in[2];
    const float* weight   = (const float*)d_in[3];
    const float* bias     = (const float*)d_in[4];
    float* out = (float*)d_out;

    float* offs = (float*)d_ws;                    // 589824 f
    float* part = offs + B * 18 * HW;              // 4*589824 f
    float* owT  = part + 4 * B * 18 * HW;          // 23040 f
    __bf16* wBhi = (__bf16*)(owT + 128 * 9 * 20);  // 147456 bf16
    __bf16* wBlo = wBhi + 36 * 128 * 32;

    wsplit_kernel<<<576, 256, 0, stream>>>(weight, wBhi, wBlo);
    otrans_kernel<<<(C * 9 * 18 + 255) / 256, 256, 0, stream>>>(offset_w, owT);
    offconv_part_kernel<<<2048, 256, 0, stream>>>(x, owT, part);
    offreduce_kernel<<<(B * 18 * HW) / 256, 256, 0, stream>>>(part, offset_b, offs);
    deform_kernel<<<1024, 256, 0, stream>>>(x, offs, wBhi, wBlo, bias, out);
}